// Round 11
// baseline (823.936 us; speedup 1.0000x reference)
//
#include <hip/hip_runtime.h>
#include <math.h>

__device__ __forceinline__ float rho(float s) { return fminf(fmaxf(s, 0.f), 1.f); }
// d/ds clip(s,0,1) with JAX maximum/minimum tie-gradient = 0.5
__device__ __forceinline__ float drho(float s) {
  if (s < 0.f || s > 1.f) return 0.f;
  float g = 1.f;
  if (s == 0.f) g *= 0.5f;
  if (s == 1.f) g *= 0.5f;
  return g;
}

// v += CTRL-shifted v within 16-lane DPP row; bound_ctrl -> 0 fill.
// row_shr moves data toward HIGHER lanes: complete 16-sum lands in lane 15.
template <int CTRL>
__device__ __forceinline__ float dpp_add(float v) {
  const int x =
      __builtin_amdgcn_update_dpp(0, __float_as_int(v), CTRL, 0xf, 0xf, true);
  return v + __int_as_float(x);
}
__device__ __forceinline__ float dpp_reduce16(float v) {
  v = dpp_add<0x118>(v);  // row_shr:8
  v = dpp_add<0x114>(v);  // row_shr:4
  v = dpp_add<0x112>(v);  // row_shr:2
  v = dpp_add<0x111>(v);  // row_shr:1  -> lane rr==15 holds the 16-sum
  return v;
}

// ---------------- Phase A: per-block partials of c0 = rho(x) @ W0 ----------
template <int ROWS>
__global__ __launch_bounds__(256) void k1_xw0(const float* __restrict__ x,
                                              const float* __restrict__ W0,
                                              const float* __restrict__ W1,
                                              float* __restrict__ part) {
  __shared__ float xs[ROWS];
  __shared__ float red[8][132];
  const int t = threadIdx.x;
  const int b = blockIdx.x;
  if (b < 128) {  // W1 prefetch into L3/L2: 128 blk x 256 thr x 16 B = 512 KB
    const float4 v = reinterpret_cast<const float4*>(W1)[b * 256 + t];
    float sv = (v.x + v.y) + (v.z + v.w);
    asm volatile("" ::"v"(sv));  // keep load alive, no store (rule #17)
  }
  const int r0 = b * ROWS;
  for (int i = t; i < ROWS; i += 256) xs[i] = rho(x[r0 + i]);
  __syncthreads();
  const int cq = t & 31;
  const int rg = t >> 5;
  constexpr int GR = ROWS / 8;
  const float4* __restrict__ W4 = reinterpret_cast<const float4*>(W0);
  float ax = 0.f, ay = 0.f, az = 0.f, aw = 0.f;
  const int base = (r0 + rg * GR) * 32 + cq;
#pragma unroll 8
  for (int i = 0; i < GR; ++i) {
    const float xv = xs[rg * GR + i];
    const float4 w = W4[base + i * 32];
    ax = fmaf(xv, w.x, ax);
    ay = fmaf(xv, w.y, ay);
    az = fmaf(xv, w.z, az);
    aw = fmaf(xv, w.w, aw);
  }
  red[rg][cq * 4 + 0] = ax;
  red[rg][cq * 4 + 1] = ay;
  red[rg][cq * 4 + 2] = az;
  red[rg][cq * 4 + 3] = aw;
  __syncthreads();
  if (t < 128) {
    float s = 0.f;
#pragma unroll
    for (int g = 0; g < 8; ++g) s += red[g][t];
    part[b * 128 + t] = s;
  }
}

// ---------------- Phase A2: tree-reduce part1 (nblk x 128) -> part2 --------
__global__ __launch_bounds__(256) void k1b_reduce(const float* __restrict__ part1,
                                                  float* __restrict__ part2) {
  __shared__ float acc[2][128];
  const int t = threadIdx.x, i = blockIdx.x;
  const int jk = t & 127, half = t >> 7;
  float s = 0.f;
  const int r0 = i * 32 + half * 16;
#pragma unroll
  for (int r = 0; r < 16; ++r) s += part1[(r0 + r) * 128 + jk];
  acc[half][jk] = s;
  __syncthreads();
  if (half == 0) part2[i * 128 + jk] = acc[0][jk] + acc[1][jk];
}

// ---------------- Phase B: ONE workgroup, W1 fully CU-resident --------------
// 256 threads (4 waves, 1 wave/SIMD -> 512-reg unified budget/wave).
// gfx950 lesson (r10): arch-addressable VGPRs cap at 256/thread; the other
// half of the unified file is AGPRs, reachable ONLY via v_accvgpr_read/write,
// and a non-MFMA kernel gets none unless forced -> force via "a" constraints.
// Thread (rr,cg): rows [8rr,8rr+8), cols [64cg,64cg+64):
//   cols  0..15 : wv0, VGPR (128 regs)
//   cols 16..43 : wa,  AGPR (224 accvgprs; volatile v_accvgpr_read per use)
//   cols 44..59 : LDS  (128 KB, slot-permuted + XOR swizzle, r10-verified)
//   cols 60..63 : wv2, VGPR (32 regs)
// Per iter: fused pass -> b = W1^T rh (DPP 16-lane reduce) and pa = W1 ro
// (staged via ap_). 2 __syncthreads/iter. Zero inter-block traffic.
__global__ __launch_bounds__(256, 1)
void k2_iter(const float* __restrict__ part2,
             const int npart2,
             const float* __restrict__ W1,
             const float* __restrict__ b1,
             const float* __restrict__ b2,
             const int* __restrict__ niterp,
             float* __restrict__ out) {
  __shared__ float wlds[256 * 128];  // 128 KB
  __shared__ float ro_[1024];
  __shared__ float rh_[128];
  __shared__ float bl_[1024];
  __shared__ float ap_[16][132];

  const int t = threadIdx.x;
  const int lane = t & 63;
  const int wvid = t >> 6;
  const int rr = lane & 15;              // rows [8rr, 8rr+8)
  const int cg = wvid * 4 + (lane >> 4); // col group in [0,16)
  const int C0 = cg * 64;

  float wv0[128];  // cols 0..15
  float wv2[32];   // cols 60..63
  float wa[224];   // cols 16..43 -> AGPRs (defined only by asm "=a" outputs)
#pragma unroll
  for (int r = 0; r < 8; ++r) {
    const float* gp = W1 + (8 * rr + r) * 1024 + C0;
#pragma unroll
    for (int i = 0; i < 4; ++i) {
      const float4 v = *reinterpret_cast<const float4*>(gp + 4 * i);
      wv0[r * 16 + 4 * i + 0] = v.x;
      wv0[r * 16 + 4 * i + 1] = v.y;
      wv0[r * 16 + 4 * i + 2] = v.z;
      wv0[r * 16 + 4 * i + 3] = v.w;
    }
    {
      const float4 v = *reinterpret_cast<const float4*>(gp + 60);
      wv2[r * 4 + 0] = v.x;
      wv2[r * 4 + 1] = v.y;
      wv2[r * 4 + 2] = v.z;
      wv2[r * 4 + 3] = v.w;
    }
    // AGPR tile: write each float4 straight into accvgprs (keeps transient
    // VGPR pressure at ~4; a bulk load-then-anchor would spill at init)
#pragma unroll
    for (int i = 0; i < 7; ++i) {
      const float4 v = *reinterpret_cast<const float4*>(gp + 16 + 4 * i);
      asm volatile("v_accvgpr_write_b32 %0, %1"
                   : "=a"(wa[r * 28 + 4 * i + 0]) : "v"(v.x));
      asm volatile("v_accvgpr_write_b32 %0, %1"
                   : "=a"(wa[r * 28 + 4 * i + 1]) : "v"(v.y));
      asm volatile("v_accvgpr_write_b32 %0, %1"
                   : "=a"(wa[r * 28 + 4 * i + 2]) : "v"(v.z));
      asm volatile("v_accvgpr_write_b32 %0, %1"
                   : "=a"(wa[r * 28 + 4 * i + 3]) : "v"(v.w));
    }
  }
  // ---- stage cols {64cg+44..64cg+59} into LDS (local k = 16cg+u) ----
  // slot s = ((k&7)<<5) + ((k>>4)<<1) + ((k>>3)&1); element (j,k) at
  // wlds[s*128 + (((j>>2)^(s&7))<<2) + (j&3)]  (r10-verified, offset 44)
  {
    const int j = t >> 1;
    const int ch = t & 1;
#pragma unroll
    for (int i = 0; i < 32; ++i) {
      const int k = ch * 128 + 4 * i;
      const float4 v = *reinterpret_cast<const float4*>(
          W1 + j * 1024 + 64 * (k >> 4) + 44 + (k & 15));
#pragma unroll
      for (int q = 0; q < 4; ++q) {
        const int kk = k + q;
        const int s = ((kk & 7) << 5) + ((kk >> 4) << 1) + ((kk >> 3) & 1);
        wlds[s * 128 + (((j >> 2) ^ (s & 7)) << 2) + (j & 3)] = (&v.x)[q];
      }
    }
  }
  // ---- init: c0 (t<128), biases, zero state ----
  float c0v = 0.f, b1v = 0.f, hreg = 0.f, mh = 0.f, vh = 0.f;
  if (t < 128) {
    if (npart2 == 32) {
      float s0 = 0.f, s1 = 0.f, s2 = 0.f, s3 = 0.f;
#pragma unroll
      for (int r = 0; r < 32; r += 4) {
        s0 += part2[(r + 0) * 128 + t];
        s1 += part2[(r + 1) * 128 + t];
        s2 += part2[(r + 2) * 128 + t];
        s3 += part2[(r + 3) * 128 + t];
      }
      c0v = (s0 + s1) + (s2 + s3);
    } else {
      float s0 = 0.f;
#pragma unroll 4
      for (int r = 0; r < npart2; ++r) s0 += part2[r * 128 + t];
      c0v = s0;
    }
    b1v = b1[t];
    rh_[t] = 0.f;
  }
  float ov[4], mo[4], vo[4], b2v[4];
#pragma unroll
  for (int q = 0; q < 4; ++q) {
    ov[q] = 0.f; mo[q] = 0.f; vo[q] = 0.f;
    b2v[q] = b2[t + 256 * q];
    ro_[t + 256 * q] = 0.f;
  }
  const int niter = *niterp;
  float pw1 = 1.f, pw2 = 1.f;
  __syncthreads();

  for (int it = 1; it <= niter; ++it) {
    pw1 *= 0.9f;
    pw2 *= 0.999f;
    const float bc1 = 1.f - pw1, bc2 = 1.f - pw2;
    float rh8[8];
    {
      const float4 ra = *reinterpret_cast<const float4*>(&rh_[8 * rr]);
      const float4 rb = *reinterpret_cast<const float4*>(&rh_[8 * rr + 4]);
      rh8[0] = ra.x; rh8[1] = ra.y; rh8[2] = ra.z; rh8[3] = ra.w;
      rh8[4] = rb.x; rh8[5] = rb.y; rh8[6] = rb.z; rh8[7] = rb.w;
    }
    float pa[8] = {0.f, 0.f, 0.f, 0.f, 0.f, 0.f, 0.f, 0.f};
#pragma unroll
    for (int sp = 0; sp < 8; ++sp) {
      float bacc[8] = {0.f, 0.f, 0.f, 0.f, 0.f, 0.f, 0.f, 0.f};
      const float4 ra = *reinterpret_cast<const float4*>(&ro_[C0 + 8 * sp]);
      const float4 rb = *reinterpret_cast<const float4*>(&ro_[C0 + 8 * sp + 4]);
#pragma unroll
      for (int q = 0; q < 8; ++q) {
        const int c = 8 * sp + q;
        const float roc = (q < 4) ? (&ra.x)[q] : (&rb.x)[q - 4];
        if (c < 16) {                       // VGPR cols
#pragma unroll
          for (int r = 0; r < 8; ++r) {
            const float we = wv0[r * 16 + c];
            bacc[q] = fmaf(rh8[r], we, bacc[q]);
            pa[r] = fmaf(we, roc, pa[r]);
          }
        } else if (c < 44) {                // AGPR cols (volatile read / use)
#pragma unroll
          for (int r = 0; r < 8; ++r) {
            float we;
            asm volatile("v_accvgpr_read_b32 %0, %1"
                         : "=v"(we) : "a"(wa[r * 28 + (c - 16)]));
            bacc[q] = fmaf(rh8[r], we, bacc[q]);
            pa[r] = fmaf(we, roc, pa[r]);
          }
        } else if (c < 60) {                // LDS cols
          const int u = c - 44;
          const int s = ((u & 7) << 5) + (cg << 1) + ((u >> 3) & 1);
          const int sw = s & 7;
          const float4* wc = reinterpret_cast<const float4*>(&wlds[s * 128]);
          const float4 A4 = wc[(2 * rr) ^ sw];      // rows 8rr..+4
          const float4 B4 = wc[(2 * rr + 1) ^ sw];  // rows 8rr+4..+8
          bacc[q] = fmaf(rh8[0], A4.x, bacc[q]);
          bacc[q] = fmaf(rh8[1], A4.y, bacc[q]);
          bacc[q] = fmaf(rh8[2], A4.z, bacc[q]);
          bacc[q] = fmaf(rh8[3], A4.w, bacc[q]);
          bacc[q] = fmaf(rh8[4], B4.x, bacc[q]);
          bacc[q] = fmaf(rh8[5], B4.y, bacc[q]);
          bacc[q] = fmaf(rh8[6], B4.z, bacc[q]);
          bacc[q] = fmaf(rh8[7], B4.w, bacc[q]);
          pa[0] = fmaf(A4.x, roc, pa[0]);
          pa[1] = fmaf(A4.y, roc, pa[1]);
          pa[2] = fmaf(A4.z, roc, pa[2]);
          pa[3] = fmaf(A4.w, roc, pa[3]);
          pa[4] = fmaf(B4.x, roc, pa[4]);
          pa[5] = fmaf(B4.y, roc, pa[5]);
          pa[6] = fmaf(B4.z, roc, pa[6]);
          pa[7] = fmaf(B4.w, roc, pa[7]);
        } else {                            // VGPR tail cols
#pragma unroll
          for (int r = 0; r < 8; ++r) {
            const float we = wv2[r * 4 + (c - 60)];
            bacc[q] = fmaf(rh8[r], we, bacc[q]);
            pa[r] = fmaf(we, roc, pa[r]);
          }
        }
      }
#pragma unroll
      for (int q = 0; q < 8; ++q) bacc[q] = dpp_reduce16(bacc[q]);
      if (rr == 15) {  // complete 16-sum lives in lane 15
        *reinterpret_cast<float4*>(&bl_[C0 + 8 * sp]) =
            make_float4(bacc[0], bacc[1], bacc[2], bacc[3]);
        *reinterpret_cast<float4*>(&bl_[C0 + 8 * sp + 4]) =
            make_float4(bacc[4], bacc[5], bacc[6], bacc[7]);
      }
    }
    // ---- stage a-partials ----
    *reinterpret_cast<float4*>(&ap_[cg][8 * rr]) =
        make_float4(pa[0], pa[1], pa[2], pa[3]);
    *reinterpret_cast<float4*>(&ap_[cg][8 * rr + 4]) =
        make_float4(pa[4], pa[5], pa[6], pa[7]);
    __syncthreads();  // bl_/ap_ valid; ro_/rh_ free to rewrite
    // ---- o-update: thread owns cols t+256q ----
#pragma unroll
    for (int q = 0; q < 4; ++q) {
      const float bs = bl_[t + 256 * q];
      const float rot = rho(ov[q]);
      const float go = drho(ov[q]) * (rot - b2v[q] - bs);
      mo[q] = 0.9f * mo[q] + 0.1f * go;
      vo[q] = 0.999f * vo[q] + 0.001f * (go * go);
      ov[q] -= 0.01f * (mo[q] / bc1) / (sqrtf(vo[q] / bc2) + 1e-8f);
      ro_[t + 256 * q] = rho(ov[q]);
    }
    // ---- h-update: thread t<128 owns row t ----
    if (t < 128) {
      float a0 = 0.f, a1 = 0.f, a2 = 0.f, a3 = 0.f;
#pragma unroll
      for (int q = 0; q < 16; q += 4) {
        a0 += ap_[q + 0][t];
        a1 += ap_[q + 1][t];
        a2 += ap_[q + 2][t];
        a3 += ap_[q + 3][t];
      }
      const float a = (a0 + a1) + (a2 + a3);
      const float rold = rho(hreg);
      const float gh = drho(hreg) * (rold - b1v - c0v - a);
      mh = 0.9f * mh + 0.1f * gh;
      vh = 0.999f * vh + 0.001f * (gh * gh);
      hreg -= 0.01f * (mh / bc1) / (sqrtf(vh / bc2) + 1e-8f);
      rh_[t] = rho(hreg);
    }
    __syncthreads();  // rh_/ro_ updated for next pass
  }
#pragma unroll
  for (int q = 0; q < 4; ++q) out[t + 256 * q] = ov[q];
}

extern "C" void kernel_launch(void* const* d_in, const int* in_sizes, int n_in,
                              void* d_out, int out_size, void* d_ws,
                              size_t ws_size, hipStream_t stream) {
  const float* x  = (const float*)d_in[0];
  // d_in[1] = b0: constant in E w.r.t. (h,o) -> never needed
  const float* b1 = (const float*)d_in[2];
  const float* b2 = (const float*)d_in[3];
  const float* W0 = (const float*)d_in[4];
  const float* W1 = (const float*)d_in[5];
  const int*   ni = (const int*)d_in[6];
  float* out = (float*)d_out;

  char* ws = (char*)d_ws;
  float* part2 = (float*)ws;             // <=32 x 128 f32 = 16 KB
  float* part1 = (float*)(ws + 16384);

  const int nrows = in_sizes[0];  // 262144
  const size_t hdr = 16384;
  int nblk1;
  if (ws_size >= hdr + (size_t)(nrows / 256) * 512) {
    nblk1 = nrows / 256;  // 1024 blocks
    hipLaunchKernelGGL(k1_xw0<256>, dim3(nblk1), dim3(256), 0, stream,
                       x, W0, W1, part1);
  } else if (ws_size >= hdr + (size_t)(nrows / 512) * 512) {
    nblk1 = nrows / 512;
    hipLaunchKernelGGL(k1_xw0<512>, dim3(nblk1), dim3(256), 0, stream,
                       x, W0, W1, part1);
  } else {
    nblk1 = nrows / 1024;
    hipLaunchKernelGGL(k1_xw0<1024>, dim3(nblk1), dim3(256), 0, stream,
                       x, W0, W1, part1);
  }
  const int nblk2 = nblk1 / 32;
  hipLaunchKernelGGL(k1b_reduce, dim3(nblk2), dim3(256), 0, stream,
                     part1, part2);
  hipLaunchKernelGGL(k2_iter, dim3(1), dim3(256), 0, stream,
                     part2, nblk2, W1, b1, b2, ni, out);
}

// Round 12
// 96.421 us; speedup vs baseline: 8.5452x; 8.5452x over previous
//
#include <hip/hip_runtime.h>
#include <math.h>

#define NBLK_B 8  // phase-B workers (cols of W1 partitioned 8 x 128)

__device__ __forceinline__ float rho(float s) {
  return fminf(fmaxf(s, 0.0f), 1.0f);
}
// d/ds clip(s,0,1) with JAX maximum/minimum tie-gradient = 0.5
__device__ __forceinline__ float drho(float s) {
  if (s < 0.0f || s > 1.0f) return 0.0f;
  float g = 1.0f;
  if (s == 0.0f) g *= 0.5f;
  if (s == 1.0f) g *= 0.5f;
  return g;
}

// ---------------- Phase A: per-block partials of c0 = rho(x) @ W0 ----------
template <int ROWS>
__global__ __launch_bounds__(256) void k1_xw0(const float* __restrict__ x,
                                              const float* __restrict__ W0,
                                              float* __restrict__ part,
                                              unsigned long long* __restrict__ aPartG) {
  __shared__ float xs[ROWS];
  __shared__ float red[8][132];
  const int t = threadIdx.x;
  const int b = blockIdx.x;
  if (b == 0) {  // zero the tagged-word region every launch (graph replay!)
#pragma unroll
    for (int i = 0; i < 16; ++i) aPartG[i * 256 + t] = 0ull;  // 4096 u64
  }
  const int r0 = b * ROWS;
  for (int i = t; i < ROWS; i += 256) xs[i] = rho(x[r0 + i]);
  __syncthreads();
  const int cq = t & 31;   // float4 column group (32 x 4 = 128 cols)
  const int rg = t >> 5;   // row group 0..7
  constexpr int GR = ROWS / 8;
  const float4* __restrict__ W4 = reinterpret_cast<const float4*>(W0);
  float ax = 0.f, ay = 0.f, az = 0.f, aw = 0.f;
  const int base = (r0 + rg * GR) * 32 + cq;
#pragma unroll 8
  for (int i = 0; i < GR; ++i) {
    const float xv = xs[rg * GR + i];
    const float4 w = W4[base + i * 32];
    ax = fmaf(xv, w.x, ax);
    ay = fmaf(xv, w.y, ay);
    az = fmaf(xv, w.z, az);
    aw = fmaf(xv, w.w, aw);
  }
  red[rg][cq * 4 + 0] = ax;
  red[rg][cq * 4 + 1] = ay;
  red[rg][cq * 4 + 2] = az;
  red[rg][cq * 4 + 3] = aw;
  __syncthreads();
  if (t < 128) {
    float s = 0.f;
#pragma unroll
    for (int g = 0; g < 8; ++g) s += red[g][t];
    part[b * 128 + t] = s;
  }
}

// ---------------- Phase A2: tree-reduce part1 (nblk x 128) -> part2 --------
__global__ __launch_bounds__(256) void k1b_reduce(const float* __restrict__ part1,
                                                  float* __restrict__ part2) {
  __shared__ float acc[2][128];
  const int t = threadIdx.x, i = blockIdx.x;
  const int jk = t & 127, half = t >> 7;
  float s = 0.f;
  const int r0 = i * 32 + half * 16;
#pragma unroll
  for (int r = 0; r < 16; ++r) s += part1[(r0 + r) * 128 + jk];
  acc[half][jk] = s;
  __syncthreads();
  if (half == 0) part2[i * 128 + jk] = acc[0][jk] + acc[1][jk];
}

// ---------------- Phase B: persistent 8-block iterator, TAGGED exchange -----
// Exchange = single 8-byte relaxed agent atomics: (tag<<32)|float_bits.
// No fences, no flags: the tag rides with the data in one indivisible word.
// Schedule: accB -> o-update -> accA -> PUBLISH a(t+1) -> consume a(t)
// (equality-poll; published 1.1 periods earlier) -> h-update.
// 4-slot ring: writer writes tag w only after consuming w-2, which implies
// every block consumed w-4 -> no overwrite-before-read. k1 zeroes tags.
__global__ __launch_bounds__(256) void k2_iter(const float* __restrict__ part2,
                                               const int npart2,
                                               const float* __restrict__ W1,
                                               const float* __restrict__ b1,
                                               const float* __restrict__ b2,
                                               const int* __restrict__ niterp,
                                               unsigned long long* __restrict__ aPartG,
                                               float* __restrict__ out) {
  __shared__ float w1s[128 * 128];  // 64 KB, elem (j,c) at j*128 + (c ^ (j&31))
  __shared__ float rhs_[128];
  __shared__ float ros_[128];
  __shared__ float c0s[128];
  __shared__ float b1s[128];
  __shared__ float bpart[2][128];
  __shared__ float apl[2][128];

  const int t = threadIdx.x;
  const int p = blockIdx.x;
  const int jk = t & 127;
  const int half = t >> 7;

  // stage W1[:, 128p:128p+128)  (row stride 1024 floats = 256 float4)
  const float4* __restrict__ W14 = reinterpret_cast<const float4*>(W1);
#pragma unroll
  for (int itr = 0; itr < 16; ++itr) {
    const int e4 = itr * 256 + t;
    const int j = e4 >> 5;
    const int c4 = e4 & 31;
    const float4 w = W14[j * 256 + p * 32 + c4];
    const int rb = j * 128;
    const int sw = j & 31;
    const int c = c4 * 4;
    w1s[rb + ((c + 0) ^ sw)] = w.x;
    w1s[rb + ((c + 1) ^ sw)] = w.y;
    w1s[rb + ((c + 2) ^ sw)] = w.z;
    w1s[rb + ((c + 3) ^ sw)] = w.w;
  }
  // c0 from part2 (<=32 rows): unrolled, fixed order, replicated bit-identical
  {
    float s = 0.f;
#pragma unroll 8
    for (int r = half; r < npart2; r += 2) s += part2[r * 128 + jk];
    bpart[half][jk] = s;
  }
  const int niter = *niterp;
  const float b2v = (half == 0) ? b2[p * 128 + jk] : 0.f;
  __syncthreads();
  if (half == 0) {
    c0s[jk] = bpart[0][jk] + bpart[1][jk];
    b1s[jk] = b1[jk];
    rhs_[jk] = 0.f;
    ros_[jk] = 0.f;
    // pre-publish a(1) = 0 with tag 1 (o_1 = 0 -> a(1) = 0)
    __hip_atomic_store(&aPartG[1 * 1024 + jk * 8 + p], 1ull << 32,
                       __ATOMIC_RELAXED, __HIP_MEMORY_SCOPE_AGENT);
  }
  __syncthreads();

  float hreg = 0.f, mh = 0.f, vh = 0.f;
  float oreg = 0.f, mo = 0.f, vo = 0.f;
  float pw1 = 1.f, pw2 = 1.f;
  const int x0 = half * 64;

  for (int it = 1; it <= niter; ++it) {
    pw1 *= 0.9f;
    pw2 *= 0.999f;
    const float bc1 = 1.0f - pw1;
    const float bc2 = 1.0f - pw2;
    // 1) accB = rho(h_t) @ W1[:,own] over own 64 rows (4-way split accum)
    {
      float a0 = 0.f, a1 = 0.f, a2 = 0.f, a3 = 0.f;
#pragma unroll
      for (int u = 0; u < 64; u += 4) {
        const int j0 = x0 + u;
        a0 = fmaf(rhs_[j0 + 0], w1s[(j0 + 0) * 128 + (jk ^ ((j0 + 0) & 31))], a0);
        a1 = fmaf(rhs_[j0 + 1], w1s[(j0 + 1) * 128 + (jk ^ ((j0 + 1) & 31))], a1);
        a2 = fmaf(rhs_[j0 + 2], w1s[(j0 + 2) * 128 + (jk ^ ((j0 + 2) & 31))], a2);
        a3 = fmaf(rhs_[j0 + 3], w1s[(j0 + 3) * 128 + (jk ^ ((j0 + 3) & 31))], a3);
      }
      bpart[half][jk] = (a0 + a1) + (a2 + a3);
    }
    __syncthreads();  // A
    // 2) o-update (purely local) -> o_{t+1}; publish rho(o_{t+1}) to LDS
    if (half == 0) {
      const float bsum = bpart[0][jk] + bpart[1][jk];
      const float rot = rho(oreg);
      const float go = drho(oreg) * (rot - b2v - bsum);
      mo = 0.9f * mo + 0.1f * go;
      vo = 0.999f * vo + 0.001f * (go * go);
      oreg = oreg - 0.01f * (mo / bc1) / (sqrtf(vo / bc2) + 1e-8f);
      ros_[jk] = rho(oreg);
    }
    __syncthreads();  // B
    // 3) accA(t+1) = W1[own cols] @ rho(o_{t+1})
    {
      float a0 = 0.f, a1 = 0.f, a2 = 0.f, a3 = 0.f;
#pragma unroll
      for (int u = 0; u < 64; u += 4) {
        const int c0i = x0 + u;
        a0 = fmaf(w1s[jk * 128 + ((c0i + 0) ^ (jk & 31))], ros_[c0i + 0], a0);
        a1 = fmaf(w1s[jk * 128 + ((c0i + 1) ^ (jk & 31))], ros_[c0i + 1], a1);
        a2 = fmaf(w1s[jk * 128 + ((c0i + 2) ^ (jk & 31))], ros_[c0i + 2], a2);
        a3 = fmaf(w1s[jk * 128 + ((c0i + 3) ^ (jk & 31))], ros_[c0i + 3], a3);
      }
      apl[half][jk] = (a0 + a1) + (a2 + a3);
    }
    __syncthreads();  // C
    // 4) PUBLISH a(t+1) as tagged words (relaxed, no fence) -- EARLY
    if (half == 0) {
      const float pav = apl[0][jk] + apl[1][jk];
      const unsigned long long wv =
          ((unsigned long long)(unsigned)(it + 1) << 32) |
          (unsigned long long)__float_as_uint(pav);
      __hip_atomic_store(&aPartG[((it + 1) & 3) * 1024 + jk * 8 + p], wv,
                         __ATOMIC_RELAXED, __HIP_MEMORY_SCOPE_AGENT);
    }
    // 5) consume a(t): equality-poll own 8 contiguous tagged words -- LATE
    //    (published ~1.1 periods ago by remotes -> expected first-try hit)
    if (half == 0) {
      unsigned long long* base = &aPartG[(it & 3) * 1024 + jk * 8];
      float ga[8];
      unsigned pend = 0xffu;
      while (pend) {
#pragma unroll
        for (int q = 0; q < 8; ++q) {
          if (pend & (1u << q)) {
            const unsigned long long wv = __hip_atomic_load(
                &base[q], __ATOMIC_RELAXED, __HIP_MEMORY_SCOPE_AGENT);
            if ((unsigned)(wv >> 32) == (unsigned)it) {
              ga[q] = __uint_as_float((unsigned)wv);
              pend &= ~(1u << q);
            }
          }
        }
        if (pend) __builtin_amdgcn_s_sleep(1);
      }
      const float a = ((ga[0] + ga[1]) + (ga[2] + ga[3])) +
                      ((ga[4] + ga[5]) + (ga[6] + ga[7]));
      // 6) h-update (replicated, bit-identical in every block)
      const float gh = drho(hreg) * (rhs_[jk] - b1s[jk] - c0s[jk] - a);
      mh = 0.9f * mh + 0.1f * gh;
      vh = 0.999f * vh + 0.001f * (gh * gh);
      hreg = hreg - 0.01f * (mh / bc1) / (sqrtf(vh / bc2) + 1e-8f);
      rhs_[jk] = rho(hreg);
    }
    __syncthreads();  // F
  }
  if (half == 0) out[p * 128 + jk] = oreg;
}

extern "C" void kernel_launch(void* const* d_in, const int* in_sizes, int n_in,
                              void* d_out, int out_size, void* d_ws,
                              size_t ws_size, hipStream_t stream) {
  const float* x  = (const float*)d_in[0];
  // d_in[1] = b0: constant in E w.r.t. (h,o) -> never needed
  const float* b1 = (const float*)d_in[2];
  const float* b2 = (const float*)d_in[3];
  const float* W0 = (const float*)d_in[4];
  const float* W1 = (const float*)d_in[5];
  const int*   ni = (const int*)d_in[6];
  float* out = (float*)d_out;

  char* ws = (char*)d_ws;
  unsigned long long* aPartG = (unsigned long long*)ws;  // 4x8x128 u64 = 32 KB
  float* part2 = (float*)(ws + 32768);                   // <=32 x 128 f32
  float* part1 = (float*)(ws + 32768 + 16384);

  const int nrows = in_sizes[0];  // 262144
  const size_t hdr = 32768 + 16384;
  int nblk1;
  if (ws_size >= hdr + (size_t)(nrows / 256) * 512) {
    nblk1 = nrows / 256;  // 1024 blocks
    hipLaunchKernelGGL(k1_xw0<256>, dim3(nblk1), dim3(256), 0, stream,
                       x, W0, part1, aPartG);
  } else if (ws_size >= hdr + (size_t)(nrows / 512) * 512) {
    nblk1 = nrows / 512;
    hipLaunchKernelGGL(k1_xw0<512>, dim3(nblk1), dim3(256), 0, stream,
                       x, W0, part1, aPartG);
  } else {
    nblk1 = nrows / 1024;
    hipLaunchKernelGGL(k1_xw0<1024>, dim3(nblk1), dim3(256), 0, stream,
                       x, W0, part1, aPartG);
  }
  const int nblk2 = nblk1 / 32;  // 32 rows per k1b block
  hipLaunchKernelGGL(k1b_reduce, dim3(nblk2), dim3(256), 0, stream,
                     part1, part2);
  hipLaunchKernelGGL(k2_iter, dim3(NBLK_B), dim3(256), 0, stream,
                     part2, nblk2, W1, b1, b2, ni, aPartG, out);
}